// Round 1
// baseline (169.268 us; speedup 1.0000x reference)
//
#include <hip/hip_runtime.h>
#include <math.h>

#define B 64
#define C 2048
#define FMH 14
#define HW 196       // 14*14
#define HW4 49       // HW / 4 (float4 columns)
#define CHUNKS 32
#define CPC (C / CHUNKS)   // 64 channels per chunk
#define NWIN 837

// Per-ratio tables (RATIOS order from reference)
__device__ __constant__ int d_RH[11]   = {4, 3, 5, 6, 5, 7, 8, 6, 10, 7, 9};
__device__ __constant__ int d_RW[11]   = {4, 5, 3, 6, 7, 5, 8, 10, 6, 9, 7};
__device__ __constant__ int d_WOFF[12] = {0, 121, 241, 361, 442, 522, 602, 651, 696, 741, 789, 837};

// ---------------- Kernel 1: channel reduction ----------------
// x viewed as [B][C][49] float4; block (chunk, b) reduces CPC channels of one
// batch into partial[b][chunk][196]. Lane = float4 column (49 of 64 active):
// each wave's load is 784 contiguous bytes -> coalesced.
__global__ __launch_bounds__(256) void sum_channels_kernel(const float4* __restrict__ x,
                                                           float4* __restrict__ partial) {
    const int chunk = blockIdx.x;
    const int b     = blockIdx.y;
    const int lane  = threadIdx.x & 63;
    const int wave  = threadIdx.x >> 6;

    float4 acc = make_float4(0.f, 0.f, 0.f, 0.f);
    if (lane < HW4) {
        const float4* base = x + (size_t)(b * C + chunk * CPC) * HW4 + lane;
        #pragma unroll 4
        for (int k = 0; k < CPC / 4; ++k) {   // 16 iters; channel = wave + 4*k
            float4 v = base[(size_t)(wave + 4 * k) * HW4];
            acc.x += v.x; acc.y += v.y; acc.z += v.z; acc.w += v.w;
        }
    }

    __shared__ float4 sh[256];
    sh[threadIdx.x] = acc;
    __syncthreads();

    if (threadIdx.x < 64 && lane < HW4) {
        float4 a0 = sh[lane], a1 = sh[64 + lane], a2 = sh[128 + lane], a3 = sh[192 + lane];
        float4 s;
        s.x = (a0.x + a1.x) + (a2.x + a3.x);
        s.y = (a0.y + a1.y) + (a2.y + a3.y);
        s.z = (a0.z + a1.z) + (a2.z + a3.z);
        s.w = (a0.w + a1.w) + (a2.w + a3.w);
        partial[(size_t)(b * CHUNKS + chunk) * HW4 + lane] = s;
    }
}

// ---------------- Kernel 2: scores + NMS, one block per batch ----------------
__device__ inline void decode_box(int w, float& x0, float& y0, float& x1, float& y1, float& area) {
    int r = 0;
    while (w >= d_WOFF[r + 1]) ++r;
    int local = w - d_WOFF[r];
    int rh = d_RH[r], rw = d_RW[r];
    int wc = FMH - rw + 1;
    int i = local / wc, j = local - i * wc;
    x0 = (float)(j * 32);
    y0 = (float)(i * 32);
    x1 = (float)((j + rw) * 32 - 1);
    y1 = (float)((i + rh) * 32 - 1);
    area = (float)(rw * 32) * (float)(rh * 32);
}

__global__ __launch_bounds__(256) void scores_nms_kernel(const float* __restrict__ partial,
                                                         float* __restrict__ out) {
    const int b   = blockIdx.x;
    const int tid = threadIdx.x;

    __shared__ float S[15][16];          // integral image, padded
    __shared__ float sc[NWIN];
    __shared__ unsigned char valid[384]; // max group size 361
    __shared__ float redv[256];
    __shared__ int   redi[256];
    __shared__ int   s_sel, s_any;
    __shared__ float s_box[4];
    __shared__ float s_area;

    // 1) y[hw] = sum over chunk partials; store into interior of S
    if (tid < HW) {
        const float* p = partial + (size_t)b * CHUNKS * HW + tid;
        float acc = 0.f;
        #pragma unroll
        for (int ch = 0; ch < CHUNKS; ++ch) acc += p[(size_t)ch * HW];
        S[tid / FMH + 1][tid % FMH + 1] = acc;
    }
    if (tid < 16) S[0][tid] = 0.f;
    if (tid < 15) S[tid][0] = 0.f;
    __syncthreads();

    // 2) integral image: row prefix then column prefix
    if (tid < 14) {
        float r = 0.f;
        for (int j = 1; j <= 14; ++j) { r += S[tid + 1][j]; S[tid + 1][j] = r; }
    }
    __syncthreads();
    if (tid < 14) {
        int j = tid + 1;
        float r = 0.f;
        for (int i = 1; i <= 14; ++i) { r += S[i][j]; S[i][j] = r; }
    }
    __syncthreads();

    // 3) window scores -> LDS + global all_scores
    for (int w = tid; w < NWIN; w += 256) {
        int r = 0;
        while (w >= d_WOFF[r + 1]) ++r;
        int local = w - d_WOFF[r];
        int rh = d_RH[r], rw = d_RW[r];
        int wc = FMH - rw + 1;
        int i = local / wc, j = local - i * wc;
        float s = (S[i + rh][j + rw] - S[i][j + rw] - S[i + rh][j] + S[i][j]) / (float)(rh * rw);
        sc[w] = s;
        out[768 + (size_t)b * NWIN + w] = s;
    }
    __syncthreads();

    // 4) greedy NMS per group
    const int GOFF[3] = {0, 361, 602};
    const int GW_[3]  = {361, 241, 235};
    const int NSEL[3] = {3, 2, 1};
    int slot = 0;
    for (int g = 0; g < 3; ++g) {
        const int off = GOFF[g], W = GW_[g];
        for (int wl = tid; wl < W; wl += 256) valid[wl] = 1;
        __syncthreads();
        int last = 0;
        for (int it = 0; it < NSEL[g]; ++it) {
            // local argmax (ascending wl => first-occurrence tie-break)
            float bv = -INFINITY; int bi = 0x7fffffff;
            for (int wl = tid; wl < W; wl += 256) {
                if (valid[wl]) {
                    float v = sc[off + wl];
                    if (v > bv || (v == bv && wl < bi)) { bv = v; bi = wl; }
                }
            }
            redv[tid] = bv; redi[tid] = bi;
            __syncthreads();
            for (int s = 128; s > 0; s >>= 1) {
                if (tid < s) {
                    if (redv[tid + s] > redv[tid] ||
                        (redv[tid + s] == redv[tid] && redi[tid + s] < redi[tid])) {
                        redv[tid] = redv[tid + s]; redi[tid] = redi[tid + s];
                    }
                }
                __syncthreads();
            }
            if (tid == 0) {
                int any = (redv[0] != -INFINITY) ? 1 : 0;
                int sel = any ? redi[0] : last;
                s_any = any; s_sel = sel;
                float x0, y0, x1, y1, area;
                decode_box(off + sel, x0, y0, x1, y1, area);
                s_box[0] = x0; s_box[1] = y0; s_box[2] = x1; s_box[3] = y1; s_area = area;
                out[(size_t)b * 6 + slot]       = (float)(off + sel);   // proposal index
                out[384 + (size_t)b * 6 + slot] = sc[off + sel];        // proposal score
            }
            __syncthreads();
            const int sel = s_sel;
            last = sel;
            if (s_any) {
                const float sx0 = s_box[0], sy0 = s_box[1], sx1 = s_box[2], sy1 = s_box[3];
                const float sa = s_area;
                for (int wl = tid; wl < W; wl += 256) {
                    if (!valid[wl]) continue;
                    float x0, y0, x1, y1, area;
                    decode_box(off + wl, x0, y0, x1, y1, area);
                    float ltx = fmaxf(x0, sx0), lty = fmaxf(y0, sy0);
                    float rbx = fminf(x1, sx1), rby = fminf(y1, sy1);
                    float wx = rbx - ltx + 1.f, wy = rby - lty + 1.f;
                    float inter = (wx < 0.f || wy < 0.f) ? 0.f : wx * wy;
                    float iou = inter / (area + sa - inter);
                    if (iou > 0.25f) valid[wl] = 0;
                }
                if (tid == 0) valid[sel] = 0;
            }
            __syncthreads();
            ++slot;
        }
    }
}

extern "C" void kernel_launch(void* const* d_in, const int* in_sizes, int n_in,
                              void* d_out, int out_size, void* d_ws, size_t ws_size,
                              hipStream_t stream) {
    const float* x = (const float*)d_in[0];
    float* out = (float*)d_out;
    float* partial = (float*)d_ws;   // B*CHUNKS*HW floats = 1.6 MB

    sum_channels_kernel<<<dim3(CHUNKS, B), 256, 0, stream>>>((const float4*)x, (float4*)partial);
    scores_nms_kernel<<<B, 256, 0, stream>>>(partial, out);
}